// Round 1
// baseline (23459.984 us; speedup 1.0000x reference)
//
#include <hip/hip_runtime.h>
#include <math.h>

// ---------------------------------------------------------------------------
// ImitateJoint: 12-step beam-search LSTM decoder.
// B=64 images, K=8 beams (BK=512 rows), T=12, H=2048, IN=2048, D=400, E=128.
// Full internal pipeline in fp64 (inputs are fp32, promoted on load) so that
// the argmax / top-k decisions match an fp64 referee to ~1e-12. Later rounds
// can lower precision once a passing baseline + counters exist.
// ---------------------------------------------------------------------------

#define BB   64
#define KK   8
#define TT   12
#define HH   2048
#define DD   400
#define EE   128
#define BKR  512          // B*K rows
#define G4   8192         // 4*H
#define KCAT 4224         // E + IN + H   (gate GEMM K after xf precompute)

// ---- workspace layout (units: doubles) ------------------------------------
static const size_t OD_H     = 0;                    // [512,2048]
static const size_t OD_C     = 1048576;              // [512,2048]
static const size_t OD_G     = 2097152;              // [512]
static const size_t OD_LOGP  = 2097664;              // [512]
static const size_t OD_SAMP  = 2098176;              // [512,12]
static const size_t OD_OUTS  = 2104320;              // [512,12]
static const size_t OD_ENT   = 2110464;              // [64]
static const size_t OD_WPQ   = 2110528;              // [64,7]
static const size_t OD_LGP   = 2110976;              // [64,7]
static const size_t STATE_END= 2111424;              // zero-init region end
static const size_t OD_Z     = 2111488;              // [512,8192] z / GEMM partials
static const size_t OD_H2    = 6305792;              // [512,2048]
static const size_t OD_C2    = 7354368;              // [512,2048]
static const size_t OD_HD    = 8402944;              // [512,2048]
static const size_t OD_EMB   = 9451520;              // [512,128]
static const size_t OD_LPT   = 9517056;              // [512,400] logp_tok
static const size_t OD_GMAT  = 9721856;              // [512,400] g
static const size_t OD_XFW   = 9926656;              // [64,8192]
static const size_t OD_BIAS  = 10450944;             // [8192]
static const size_t OD_INTS  = 10459136;             // 1024 ints (order, greedy)
static const size_t OD_TOTAL = 10459648;             // doubles (~83.7 MB)

// ---------------------------------------------------------------------------
// Generic f64 GEMM, C[M,N] = A[M,K] * B[N,K]^T (B is N-major / row per output
// col-block, exactly how W_* are stored). A is up to 3 concatenated segments
// (each f32 or f64); B up to 2 f32 segments. Optional split-K partials.
// BM=128, BN=128, BK=8, 256 threads, 8x8 micro-tile, double-buffered LDS.
// B-fragment = 2-wide column groups at stride 32 -> 2-way LDS aliasing (free).
// ---------------------------------------------------------------------------
#define GBM 128
#define GBN 128
#define GBK 8

__global__ __launch_bounds__(256)
void ij_gemm_f64(const void* __restrict__ A0, const void* __restrict__ A1,
                 const void* __restrict__ A2,
                 int adt0, int adt1, int adt2, int kA1, int kA2,
                 int lda0, int lda1, int lda2,
                 const float* __restrict__ B0, const float* __restrict__ B1,
                 int kB1, int ldb0, int ldb1,
                 double* __restrict__ C, int M, int N, int Ktot, int Klen,
                 const double* __restrict__ rowAdd, const double* __restrict__ colBias,
                 int relu_flag, int partial_flag)
{
    __shared__ double As[2][GBK][GBM];
    __shared__ double Bs[2][GBK][GBN];

    const int tid = threadIdx.x;
    const int tx  = tid & 15;        // N direction (16)
    const int ty  = tid >> 4;        // M direction (16)
    const int n0  = blockIdx.x * GBN;
    const int m0  = blockIdx.y * GBM;
    const int kstart = blockIdx.z * Klen;
    int kend = kstart + Klen; if (kend > Ktot) kend = Ktot;
    const int nch = (kend - kstart) / GBK;
    double* Cout = C + (size_t)blockIdx.z * ((size_t)M * (size_t)N);

    const int sr  = tid & 127;       // staging row within tile
    const int skq = tid >> 7;        // staging k-quad (0..1)

    double aReg[4];
    float4 bReg;

    auto loadChunk = [&](int kb) {
        const void* ap; int adt, lda, ka;
        if (kb < kA1)      { ap = A0; adt = adt0; lda = lda0; ka = kb; }
        else if (kb < kA2) { ap = A1; adt = adt1; lda = lda1; ka = kb - kA1; }
        else               { ap = A2; adt = adt2; lda = lda2; ka = kb - kA2; }
        const float* bp; int ldb, kb2;
        if (kb < kB1) { bp = B0; ldb = ldb0; kb2 = kb; }
        else          { bp = B1; ldb = ldb1; kb2 = kb - kB1; }

        const int arow = m0 + sr;
        const int acol = ka + skq * 4;
        if (arow < M) {
            if (adt) {
                const double* apd = (const double*)ap + (size_t)arow * lda + acol;
                double2 d0 = *(const double2*)(apd);
                double2 d1 = *(const double2*)(apd + 2);
                aReg[0] = d0.x; aReg[1] = d0.y; aReg[2] = d1.x; aReg[3] = d1.y;
            } else {
                float4 f = *(const float4*)((const float*)ap + (size_t)arow * lda + acol);
                aReg[0] = f.x; aReg[1] = f.y; aReg[2] = f.z; aReg[3] = f.w;
            }
        } else {
            aReg[0] = aReg[1] = aReg[2] = aReg[3] = 0.0;
        }
        const int brow = n0 + sr;
        if (brow < N) bReg = *(const float4*)(bp + (size_t)brow * ldb + kb2 + skq * 4);
        else          bReg = make_float4(0.f, 0.f, 0.f, 0.f);
    };
    auto storeChunk = [&](int bsel) {
        const int k4 = skq * 4;
        As[bsel][k4+0][sr] = aReg[0];
        As[bsel][k4+1][sr] = aReg[1];
        As[bsel][k4+2][sr] = aReg[2];
        As[bsel][k4+3][sr] = aReg[3];
        Bs[bsel][k4+0][sr] = (double)bReg.x;
        Bs[bsel][k4+1][sr] = (double)bReg.y;
        Bs[bsel][k4+2][sr] = (double)bReg.z;
        Bs[bsel][k4+3][sr] = (double)bReg.w;
    };

    double acc[8][8];
#pragma unroll
    for (int i = 0; i < 8; ++i)
#pragma unroll
        for (int j = 0; j < 8; ++j) acc[i][j] = 0.0;

    loadChunk(kstart);
    storeChunk(0);
    __syncthreads();
    int bsel = 0;
    for (int c = 0; c < nch; ++c) {
        if (c + 1 < nch) loadChunk(kstart + (c + 1) * GBK);
#pragma unroll
        for (int kkk = 0; kkk < GBK; ++kkk) {
            double a[8], b[8];
            const double* ar = &As[bsel][kkk][ty * 8];
#pragma unroll
            for (int i = 0; i < 8; ++i) a[i] = ar[i];
            const double* br = &Bs[bsel][kkk][tx * 2];
#pragma unroll
            for (int g2 = 0; g2 < 4; ++g2) {
                b[g2*2+0] = br[g2*32+0];
                b[g2*2+1] = br[g2*32+1];
            }
#pragma unroll
            for (int i = 0; i < 8; ++i)
#pragma unroll
                for (int j = 0; j < 8; ++j)
                    acc[i][j] = fma(a[i], b[j], acc[i][j]);
        }
        if (c + 1 < nch) storeChunk(bsel ^ 1);
        __syncthreads();
        bsel ^= 1;
    }

    // epilogue
    const bool fullN = (n0 + GBN <= N);
#pragma unroll
    for (int i = 0; i < 8; ++i) {
        const int row = m0 + ty * 8 + i;
        if (row >= M) continue;
        const size_t rbase = (size_t)row * N;
        const double* ra = rowAdd ? (rowAdd + (size_t)(row & 63) * N) : (const double*)0;
#pragma unroll
        for (int g2 = 0; g2 < 4; ++g2) {
            const int col = n0 + tx * 2 + g2 * 32;
            double v0 = acc[i][g2*2+0];
            double v1 = acc[i][g2*2+1];
            if (fullN) {
                if (!partial_flag) {
                    if (ra)        { v0 += ra[col];       v1 += ra[col+1]; }
                    if (colBias)   { v0 += colBias[col];  v1 += colBias[col+1]; }
                    if (relu_flag) { v0 = fmax(v0, 0.0);  v1 = fmax(v1, 0.0); }
                }
                double2 st; st.x = v0; st.y = v1;
                *(double2*)(Cout + rbase + col) = st;
            } else {
                if (col < N) {
                    double v = v0;
                    if (!partial_flag) {
                        if (ra)        v += ra[col];
                        if (colBias)   v += colBias[col];
                        if (relu_flag) v = fmax(v, 0.0);
                    }
                    Cout[rbase + col] = v;
                }
                if (col + 1 < N) {
                    double v = v1;
                    if (!partial_flag) {
                        if (ra)        v += ra[col+1];
                        if (colBias)   v += colBias[col+1];
                        if (relu_flag) v = fmax(v, 0.0);
                    }
                    Cout[rbase + col + 1] = v;
                }
            }
        }
    }
}

// ---------------------------------------------------------------------------
__global__ void ij_bias_kernel(const float* __restrict__ b_ih, const float* __restrict__ b_hh,
                               double* __restrict__ bias)
{
    int i = blockIdx.x * 256 + threadIdx.x;
    if (i < G4) bias[i] = (double)b_ih[i] + (double)b_hh[i];
}

// emb[r,e] = relu(W_emb[e, pop[r]] + b_emb[e])
__global__ void ij_emb_kernel(const float* __restrict__ W_emb, const float* __restrict__ b_emb,
                              const int* __restrict__ pop_t, double* __restrict__ emb)
{
    int i = blockIdx.x * 256 + threadIdx.x;
    if (i >= BKR * EE) return;
    int r = i >> 7, e = i & 127;
    double v = (double)W_emb[e * DD + pop_t[r]] + (double)b_emb[e];
    emb[i] = v > 0.0 ? v : 0.0;
}

// LSTM elementwise: gates packed [i|f|g|o] along 8192
__global__ void ij_lstm_kernel(const double* __restrict__ z, const double* __restrict__ c,
                               double* __restrict__ h2, double* __restrict__ c2)
{
    int i = blockIdx.x * 256 + threadIdx.x;
    if (i >= BKR * HH) return;
    int r = i >> 11, hh = i & 2047;
    const double* zr = z + (size_t)r * G4;
    double iv = zr[hh], fv = zr[HH + hh], gv = zr[2*HH + hh], ov = zr[3*HH + hh];
    double si = 1.0 / (1.0 + exp(-iv));
    double sf = 1.0 / (1.0 + exp(-fv));
    double so = 1.0 / (1.0 + exp(-ov));
    double cv = sf * c[i] + si * tanh(gv);
    c2[i] = cv;
    h2[i] = so * tanh(cv);
}

__global__ void ij_reduce_fc1_kernel(const double* __restrict__ part, const float* __restrict__ b_fc1,
                                     double* __restrict__ hd)
{
    int i = blockIdx.x * 256 + threadIdx.x;
    if (i >= BKR * HH) return;
    double v = part[i] + part[i + 1048576] + part[i + 2097152] + part[i + 3145728]
             + (double)b_fc1[i & 2047];
    hd[i] = v > 0.0 ? v : 0.0;
}

__global__ void ij_reduce_xfw_kernel(const double* __restrict__ part, double* __restrict__ xfw)
{
    int i = blockIdx.x * 256 + threadIdx.x;
    if (i >= BB * G4) return;
    xfw[i] = part[i] + part[i + 524288] + part[i + 1048576] + part[i + 1572864];
}

// ---------------------------------------------------------------------------
// Per-row (512 blocks): reduce 16 split-K logits partials + b_out + mask row,
// log_softmax, greedy argmax (lowest index on tie), and the Gumbel-with-max
// conditioned scores g.
// ---------------------------------------------------------------------------
__global__ __launch_bounds__(256)
void ij_softmax_g_kernel(const double* __restrict__ part, const float* __restrict__ b_out,
                         const float* __restrict__ mask_table, const int* __restrict__ pop_t,
                         const float* __restrict__ gum_t, const double* __restrict__ G,
                         const double* __restrict__ logp,
                         double* __restrict__ logp_tok, double* __restrict__ gmat,
                         int* __restrict__ greedy)
{
    const int r = blockIdx.x, tid = threadIdx.x;
    __shared__ double sred[256];
    __shared__ int    sidx[256];
    __shared__ double sbc[2];

    const int pop = pop_t[r];
    const int j0 = tid, j1 = tid + 256;
    double lg0 = -INFINITY, lg1 = -INFINITY;
    if (j0 < DD) {
        double v = (double)b_out[j0] + (double)mask_table[pop * DD + j0];
#pragma unroll
        for (int s = 0; s < 16; ++s) v += part[(size_t)s * (BKR*DD) + (size_t)r * DD + j0];
        lg0 = v;
    }
    if (j1 < DD) {
        double v = (double)b_out[j1] + (double)mask_table[pop * DD + j1];
#pragma unroll
        for (int s = 0; s < 16; ++s) v += part[(size_t)s * (BKR*DD) + (size_t)r * DD + j1];
        lg1 = v;
    }
    // argmax (value desc, index asc)
    double mv = lg0; int mi = j0;
    if (lg1 > mv) { mv = lg1; mi = j1; }
    sred[tid] = mv; sidx[tid] = mi;
    __syncthreads();
    for (int off = 128; off > 0; off >>= 1) {
        if (tid < off) {
            double ov = sred[tid+off]; int oi = sidx[tid+off];
            if (ov > sred[tid] || (ov == sred[tid] && oi < sidx[tid])) { sred[tid] = ov; sidx[tid] = oi; }
        }
        __syncthreads();
    }
    if (tid == 0) { sbc[0] = sred[0]; greedy[r] = sidx[0]; }
    __syncthreads();
    const double rowmax = sbc[0];

    double es = 0.0;
    if (j0 < DD) es += exp(lg0 - rowmax);
    if (j1 < DD) es += exp(lg1 - rowmax);
    __syncthreads();
    sred[tid] = es;
    __syncthreads();
    for (int off = 128; off > 0; off >>= 1) {
        if (tid < off) sred[tid] += sred[tid+off];
        __syncthreads();
    }
    if (tid == 0) sbc[1] = log(sred[0]);
    __syncthreads();
    const double lse = sbc[1];
    const double lpr = logp[r], Gr = G[r];

    double lt0 = 0.0, lt1 = 0.0, gp0 = -INFINITY, gp1 = -INFINITY;
    if (j0 < DD) {
        lt0 = lg0 - rowmax - lse;
        logp_tok[(size_t)r * DD + j0] = lt0;
        double u = (double)gum_t[(size_t)r * DD + j0];
        u = fmin(fmax(u, 1e-9), 1.0 - 1e-9);
        gp0 = lt0 + lpr + (-log(-log(u)));
    }
    if (j1 < DD) {
        lt1 = lg1 - rowmax - lse;
        logp_tok[(size_t)r * DD + j1] = lt1;
        double u = (double)gum_t[(size_t)r * DD + j1];
        u = fmin(fmax(u, 1e-9), 1.0 - 1e-9);
        gp1 = lt1 + lpr + (-log(-log(u)));
    }
    __syncthreads();
    sred[tid] = fmax(gp0, gp1);
    __syncthreads();
    for (int off = 128; off > 0; off >>= 1) {
        if (tid < off) sred[tid] = fmax(sred[tid], sred[tid+off]);
        __syncthreads();
    }
    const double Z = sred[0];
    if (j0 < DD) {
        double v = Gr - gp0 + log1p(-exp(gp0 - Z));
        gmat[(size_t)r * DD + j0] = Gr - fmax(v, 0.0) - log1p(exp(-fabs(v)));
    }
    if (j1 < DD) {
        double v = Gr - gp1 + log1p(-exp(gp1 - Z));
        gmat[(size_t)r * DD + j1] = Gr - fmax(v, 0.0) - log1p(exp(-fabs(v)));
    }
}

// ---------------------------------------------------------------------------
// One block per image b. Top-8 of the 3200 candidates (descending, lower
// index on ties == jax.lax.top_k), then all beam bookkeeping. Beam rows for
// image b are {s*64+b}, so blocks are fully independent.
// ---------------------------------------------------------------------------
__global__ __launch_bounds__(256)
void ij_beam_kernel(const double* __restrict__ gmat, const double* __restrict__ logp_tok,
                    const int* __restrict__ greedy, const int* __restrict__ pop_t,
                    const float* __restrict__ mask_table,
                    double* __restrict__ G, double* __restrict__ logp,
                    double* __restrict__ samples, double* __restrict__ outs,
                    double* __restrict__ entacc, double* __restrict__ wpq,
                    double* __restrict__ lgp_o, int* __restrict__ order_g, int t)
{
    const int b = blockIdx.x, tid = threadIdx.x;
    __shared__ double sv[256];
    __shared__ int    si2[256];
    __shared__ double gval8[8];
    __shared__ int    gidx8[8];
    __shared__ int    ord8[8], smp8[8];
    __shared__ double lp28[8], sel8[8], Gn8[8];
    __shared__ double oldS[8][TT], oldO[8][TT];
    __shared__ double efull[8];

    if (t > 0) {
        for (int pass = 0; pass < 8; ++pass) {
            double bv = -INFINITY; int bi = 0x7fffffff;
            for (int cand = tid; cand < KK * DD; cand += 256) {
                bool used = false;
                for (int p = 0; p < pass; ++p) used |= (gidx8[p] == cand);
                if (used) continue;
                int kb2 = cand / DD, d = cand - kb2 * DD;
                double v = gmat[(size_t)(kb2 * BB + b) * DD + d];
                if (v > bv || (v == bv && cand < bi)) { bv = v; bi = cand; }
            }
            sv[tid] = bv; si2[tid] = bi;
            __syncthreads();
            for (int off = 128; off > 0; off >>= 1) {
                if (tid < off) {
                    double ov = sv[tid+off]; int oi = si2[tid+off];
                    if (ov > sv[tid] || (ov == sv[tid] && oi < si2[tid])) { sv[tid] = ov; si2[tid] = oi; }
                }
                __syncthreads();
            }
            if (tid == 0) { gval8[pass] = sv[0]; gidx8[pass] = si2[0]; }
            __syncthreads();
        }
    }

    // slot bookkeeping (reads of old logp/G happen here, writes after sync)
    if (tid < 8) {
        const int s = tid, rp = s * BB + b;
        int ord, smp; double Gn;
        if (t == 0) { ord = rp; smp = greedy[rp]; Gn = G[rp]; }
        else {
            int idx = gidx8[s]; int kb2 = idx / DD;
            ord = kb2 * BB + b; smp = idx - kb2 * DD; Gn = gval8[s];
        }
        ord8[s] = ord; smp8[s] = smp; Gn8[s] = Gn;
        double sel = logp_tok[(size_t)ord * DD + smp];
        double lp2 = (t == 0) ? logp[ord] : logp[ord] + sel;
        sel8[s] = sel; lp28[s] = lp2;
    }
    __syncthreads();
    if (tid < 8 * TT) {
        int s = tid / TT, ttc = tid - s * TT;
        oldS[s][ttc] = samples[ord8[s] * TT + ttc];
        oldO[s][ttc] = outs[ord8[s] * TT + ttc];
    }
    __syncthreads();
    if (tid < 8 * TT) {
        int s = tid / TT, ttc = tid - s * TT;
        int rp = s * BB + b;
        samples[rp * TT + ttc] = (ttc == t) ? (double)smp8[s] : oldS[s][ttc];
        outs[rp * TT + ttc]    = (ttc == t) ? sel8[s]         : oldO[s][ttc];
    }
    if (tid >= 96 && tid < 104) {
        int s = tid - 96, rp = s * BB + b;
        G[rp]       = Gn8[s];
        logp[rp]    = lp28[s];
        order_g[rp] = ord8[s];
    }

    if (t > 0) {
        // importance-weighted entropy update (7 live beams)
        for (int s = 0; s < KK - 1; ++s) {
            const int ord = ord8[s];
            const double* lrow = logp_tok + (size_t)ord * DD;
            const float*  mrow = mask_table + (size_t)pop_t[ord] * DD;
            double acc = 0.0;
            for (int j = tid; j < DD; j += 256) {
                double lp_ = lrow[j];
                if (mrow[j] == 0.0f) acc += lp_ * exp(lp_);
            }
            __syncthreads();
            sv[tid] = acc;
            __syncthreads();
            for (int off = 128; off > 0; off >>= 1) {
                if (tid < off) sv[tid] += sv[tid+off];
                __syncthreads();
            }
            if (tid == 0) efull[s] = sv[0];
            __syncthreads();
        }
        if (tid == 0) {
            const double gk = gval8[7];
            double sw = 0.0, swe = 0.0;
            for (int s = 0; s < KK - 1; ++s) {
                double phi = lp28[s];
                double x = gk - phi;
                double y = exp(-x);
                double gls;
                if (x >= 10.0) gls = -x - y * 0.5 + y * y * (1.0 / 24.0);
                else           gls = log(-expm1(-exp(-fmin(x, 10.0))));
                double w = exp(phi - gls);
                wpq[b * (KK-1) + s]   = w;
                lgp_o[b * (KK-1) + s] = phi;
                sw += w; swe += w * efull[s];
            }
            entacc[b] += swe / sw;
        }
    }
}

__global__ void ij_permute_kernel(const double* __restrict__ h2, const double* __restrict__ c2,
                                  const int* __restrict__ order_g,
                                  double* __restrict__ h, double* __restrict__ c)
{
    int i = blockIdx.x * 256 + threadIdx.x;
    if (i >= BKR * HH) return;
    int r = i >> 11, j = i & 2047;
    int o = order_g[r];
    h[i] = h2[(size_t)o * HH + j];
    c[i] = c2[(size_t)o * HH + j];
}

__global__ void ij_final_kernel(const double* __restrict__ outs, const double* __restrict__ samples,
                                const double* __restrict__ entacc, const double* __restrict__ wpq,
                                const double* __restrict__ lgp_o, float* __restrict__ out)
{
    int i = blockIdx.x * 256 + threadIdx.x;
    if (i < 5376) {
        int bb = i / 84, rest = i - bb * 84;
        int s = rest / TT, ttc = rest - s * TT;
        size_t src = (size_t)(s * BB + bb) * TT + ttc;
        out[i]        = (float)outs[src];
        out[5376 + i] = (float)samples[src];
    } else if (i < 5440) {
        out[10752 + (i - 5376)] = (float)entacc[i - 5376];
    } else if (i < 5888) {
        int q = i - 5440; out[10816 + q] = (float)wpq[q];
    } else if (i < 6336) {
        int q = i - 5888; out[11264 + q] = (float)lgp_o[q];
    }
}

// ---------------------------------------------------------------------------
extern "C" void kernel_launch(void* const* d_in, const int* in_sizes, int n_in,
                              void* d_out, int out_size, void* d_ws, size_t ws_size,
                              hipStream_t stream)
{
    const float* x_f   = (const float*)d_in[0];
    const float* x_f3  = (const float*)d_in[1];
    const float* gum   = (const float*)d_in[2];
    const int*   pop   = (const int*)d_in[3];
    const float* mask  = (const float*)d_in[4];
    const float* W_emb = (const float*)d_in[5];
    const float* b_emb = (const float*)d_in[6];
    const float* W_ih  = (const float*)d_in[7];
    const float* W_hh  = (const float*)d_in[8];
    const float* b_ih  = (const float*)d_in[9];
    const float* b_hh  = (const float*)d_in[10];
    const float* b_fc1 = (const float*)d_in[12];
    const float* W_fc1 = (const float*)d_in[11];
    const float* W_out = (const float*)d_in[13];
    const float* b_out = (const float*)d_in[14];
    float*  out = (float*)d_out;
    double* wsd = (double*)d_ws;

    if (ws_size < OD_TOTAL * sizeof(double)) return;  // need ~84 MB scratch

    double* H    = wsd + OD_H;
    double* Cc   = wsd + OD_C;
    double* Gv   = wsd + OD_G;
    double* LOGP = wsd + OD_LOGP;
    double* SAMP = wsd + OD_SAMP;
    double* OUTS = wsd + OD_OUTS;
    double* ENT  = wsd + OD_ENT;
    double* WPQ  = wsd + OD_WPQ;
    double* LGP  = wsd + OD_LGP;
    double* Z    = wsd + OD_Z;
    double* H2   = wsd + OD_H2;
    double* C2   = wsd + OD_C2;
    double* HD   = wsd + OD_HD;
    double* EMB  = wsd + OD_EMB;
    double* LPT  = wsd + OD_LPT;
    double* GMAT = wsd + OD_GMAT;
    double* XFW  = wsd + OD_XFW;
    double* BIAS = wsd + OD_BIAS;
    int* ORDER   = (int*)(wsd + OD_INTS);
    int* GREEDY  = ORDER + 512;

    // zero h, c, G, logp, samples, outs, ent, wpq, lgp
    hipMemsetAsync(wsd, 0, STATE_END * sizeof(double), stream);
    ij_bias_kernel<<<32, 256, 0, stream>>>(b_ih, b_hh, BIAS);

    // xfW = x_f @ W_ih[:, :2048]^T   (split-K=4 partials into Z, then reduce)
    ij_gemm_f64<<<dim3(64, 1, 4), 256, 0, stream>>>(
        x_f, nullptr, nullptr, 0, 0, 0, 2048, 2048, 2048, 0, 0,
        W_ih, nullptr, 2048, 4224, 0,
        Z, BB, G4, 2048, 512, nullptr, nullptr, 0, 1);
    ij_reduce_xfw_kernel<<<2048, 256, 0, stream>>>(Z, XFW);

    for (int t = 0; t < TT; ++t) {
        const int* pop_t = pop + t * BKR;
        ij_emb_kernel<<<256, 256, 0, stream>>>(W_emb, b_emb, pop_t, EMB);

        // gate GEMM: A = [emb | xf3_t | h], B = [W_ih cols 2048..4223 | W_hh]
        // epilogue adds xfW[row%64] + (b_ih+b_hh)
        ij_gemm_f64<<<dim3(64, 4, 1), 256, 0, stream>>>(
            EMB, x_f3 + (size_t)t * BKR * 2048, H, 1, 0, 1, 128, 2176, 128, 2048, 2048,
            W_ih + 2048, W_hh, 2176, 4224, 2048,
            Z, BKR, G4, KCAT, KCAT, XFW, BIAS, 0, 0);

        ij_lstm_kernel<<<4096, 256, 0, stream>>>(Z, Cc, H2, C2);

        // fc1 (split-K=4 into Z, reduce w/ bias+relu)
        ij_gemm_f64<<<dim3(16, 4, 4), 256, 0, stream>>>(
            H2, nullptr, nullptr, 1, 0, 0, 2048, 2048, 2048, 0, 0,
            W_fc1, nullptr, 2048, 2048, 0,
            Z, BKR, HH, 2048, 512, nullptr, nullptr, 0, 1);
        ij_reduce_fc1_kernel<<<4096, 256, 0, stream>>>(Z, b_fc1, HD);

        // logits (split-K=16 into Z; reduce folded into softmax kernel)
        ij_gemm_f64<<<dim3(4, 4, 16), 256, 0, stream>>>(
            HD, nullptr, nullptr, 1, 0, 0, 2048, 2048, 2048, 0, 0,
            W_out, nullptr, 2048, 2048, 0,
            Z, BKR, DD, 2048, 128, nullptr, nullptr, 0, 1);

        ij_softmax_g_kernel<<<512, 256, 0, stream>>>(
            Z, b_out, mask, pop_t, gum + (size_t)t * BKR * DD,
            Gv, LOGP, LPT, GMAT, GREEDY);

        ij_beam_kernel<<<64, 256, 0, stream>>>(
            GMAT, LPT, GREEDY, pop_t, mask,
            Gv, LOGP, SAMP, OUTS, ENT, WPQ, LGP, ORDER, t);

        ij_permute_kernel<<<4096, 256, 0, stream>>>(H2, C2, ORDER, H, Cc);
    }

    ij_final_kernel<<<25, 256, 0, stream>>>(OUTS, SAMP, ENT, WPQ, LGP, out);
    (void)in_sizes; (void)n_in; (void)out_size;
}

// Round 2
// 9715.845 us; speedup vs baseline: 2.4146x; 2.4146x over previous
//
#include <hip/hip_runtime.h>
#include <math.h>

// ---------------------------------------------------------------------------
// ImitateJoint: 12-step beam-search LSTM decoder.
// B=64 images, K=8 beams (BK=512 rows), T=12, H=2048, IN=2048, D=400, E=128.
// Round 2: GEMMs in fp32 (157 TF peak vs 78.6 f64) with >=4 blocks/CU
// (BN=64 + split-K). All decision-critical math (log_softmax, Gumbel g,
// top-k, entropy weights) stays fp64. If this round fails correctness
// (top-k flip), fall back to f64 GEMM dtype keeping this structure.
// ---------------------------------------------------------------------------

#define BB   64
#define KK   8
#define TT   12
#define HH   2048
#define DD   400
#define EE   128
#define BKR  512          // B*K rows
#define G4   8192         // 4*H
#define KCAT 4224         // E + IN + H   (gate GEMM K after xf precompute)

// ---- workspace layout (byte offsets) --------------------------------------
// f64 state block (zeroed): G[512] LOGP[512] SAMP[512*12] OUTS[512*12]
//                           ENT[64] WPQ[64*7] LGP[64*7]
static const size_t OFF_STATE = 0;                // doubles, 14272 used
static const size_t OFF_H     = 114688;           // float [512][2048]
static const size_t OFF_C     = 4308992;          // float [512][2048]
static const size_t ZERO_END  = 8503296;          // memset 0 .. here
static const size_t OFF_Z     = 8503296;          // float, 2*512*8192 partials
static const size_t OFF_H2    = 42057728;         // float [512][2048]
static const size_t OFF_C2    = 46252032;         // float [512][2048]
static const size_t OFF_HD    = 50446336;         // float [512][2048]
static const size_t OFF_EMB   = 54640640;         // float [512][128]
static const size_t OFF_XFW   = 54902784;         // float [64][8192]
static const size_t OFF_BIAS  = 56999936;         // float [8192]
static const size_t OFF_LPT   = 57032704;         // double [512][400]
static const size_t OFF_GMAT  = 58671104;         // double [512][400]
static const size_t OFF_INTS  = 60309504;         // int [1024]
static const size_t WS_TOTAL  = 60313600;         // ~57.5 MB

// double-state indices (in doubles, relative to OFF_STATE)
#define SI_G    0
#define SI_LOGP 512
#define SI_SAMP 1024
#define SI_OUTS 7168
#define SI_ENT  13312
#define SI_WPQ  13376
#define SI_LGP  13824

// ---------------------------------------------------------------------------
// fp32 GEMM, partial-sum producer: C[z][M][N] += A[M,K_z] * B[N,K_z]^T.
// A up to 3 concatenated fp32 segments; B up to 2 fp32 segments (weights are
// stored N-major = one row per output column). BM=128, BN=64, BK=16,
// 256 threads, 8x4 micro-tile, double-buffered LDS. Fragment reads are
// broadcast / 2-way (free); staging writes are 4-way (12 instrs/chunk,
// negligible vs 512 fma-instrs/chunk).
// ---------------------------------------------------------------------------
#define FBM 128
#define FBN 64
#define FBK 16

__global__ __launch_bounds__(256, 2)
void ij_gemm_f32(const float* __restrict__ A0, const float* __restrict__ A1,
                 const float* __restrict__ A2, int kA1, int kA2,
                 int lda0, int lda1, int lda2,
                 const float* __restrict__ B0, const float* __restrict__ B1,
                 int kB1, int ldb0, int ldb1,
                 float* __restrict__ C, int M, int N, int Klen)
{
    __shared__ float As[2][FBK][FBM];
    __shared__ float Bs[2][FBK][FBN];

    const int tid = threadIdx.x;
    const int tx  = tid & 15;            // N direction (16 cols of 2x2)
    const int ty  = tid >> 4;            // M direction (16 rows of 8)
    const int n0  = blockIdx.x * FBN;
    const int m0  = blockIdx.y * FBM;
    const int kstart = blockIdx.z * Klen;
    const int nch = Klen / FBK;
    float* Cout = C + (size_t)blockIdx.z * ((size_t)M * (size_t)N);

    const int srow = tid >> 2;           // 0..63 staging row
    const int kq   = tid & 3;            // k-quad within chunk

    float4 aR0, aR1, bR;

    auto loadChunk = [&](int kb0) {
        const int kc = kb0 + kq * 4;
        const float* ap; int ao, ld;
        if (kc < kA1)      { ap = A0; ao = kc;       ld = lda0; }
        else if (kc < kA2) { ap = A1; ao = kc - kA1; ld = lda1; }
        else               { ap = A2; ao = kc - kA2; ld = lda2; }
        const int r0 = m0 + srow, r1 = r0 + 64;
        aR0 = (r0 < M) ? *(const float4*)(ap + (size_t)r0 * ld + ao)
                       : make_float4(0.f, 0.f, 0.f, 0.f);
        aR1 = (r1 < M) ? *(const float4*)(ap + (size_t)r1 * ld + ao)
                       : make_float4(0.f, 0.f, 0.f, 0.f);
        const float* bp; int bo, bld;
        if (kc < kB1) { bp = B0; bo = kc;       bld = ldb0; }
        else          { bp = B1; bo = kc - kB1; bld = ldb1; }
        const int bn = n0 + srow;
        bR = (bn < N) ? *(const float4*)(bp + (size_t)bn * bld + bo)
                      : make_float4(0.f, 0.f, 0.f, 0.f);
    };
    auto storeChunk = [&](int bsel) {
        const int k4 = kq * 4;
        As[bsel][k4+0][srow]      = aR0.x;
        As[bsel][k4+1][srow]      = aR0.y;
        As[bsel][k4+2][srow]      = aR0.z;
        As[bsel][k4+3][srow]      = aR0.w;
        As[bsel][k4+0][srow + 64] = aR1.x;
        As[bsel][k4+1][srow + 64] = aR1.y;
        As[bsel][k4+2][srow + 64] = aR1.z;
        As[bsel][k4+3][srow + 64] = aR1.w;
        Bs[bsel][k4+0][srow]      = bR.x;
        Bs[bsel][k4+1][srow]      = bR.y;
        Bs[bsel][k4+2][srow]      = bR.z;
        Bs[bsel][k4+3][srow]      = bR.w;
    };

    float acc[8][4];
#pragma unroll
    for (int i = 0; i < 8; ++i)
#pragma unroll
        for (int j = 0; j < 4; ++j) acc[i][j] = 0.f;

    loadChunk(kstart);
    storeChunk(0);
    __syncthreads();
    int bsel = 0;
    for (int c = 0; c < nch; ++c) {
        if (c + 1 < nch) loadChunk(kstart + (c + 1) * FBK);
#pragma unroll
        for (int kkk = 0; kkk < FBK; ++kkk) {
            float a[8], b[4];
            const float4 av0 = *(const float4*)&As[bsel][kkk][ty * 8];
            const float4 av1 = *(const float4*)&As[bsel][kkk][ty * 8 + 4];
            a[0]=av0.x; a[1]=av0.y; a[2]=av0.z; a[3]=av0.w;
            a[4]=av1.x; a[5]=av1.y; a[6]=av1.z; a[7]=av1.w;
            const float2 bv0 = *(const float2*)&Bs[bsel][kkk][tx * 2];
            const float2 bv1 = *(const float2*)&Bs[bsel][kkk][tx * 2 + 32];
            b[0]=bv0.x; b[1]=bv0.y; b[2]=bv1.x; b[3]=bv1.y;
#pragma unroll
            for (int i = 0; i < 8; ++i)
#pragma unroll
                for (int j = 0; j < 4; ++j)
                    acc[i][j] = fmaf(a[i], b[j], acc[i][j]);
        }
        if (c + 1 < nch) storeChunk(bsel ^ 1);
        __syncthreads();
        bsel ^= 1;
    }

#pragma unroll
    for (int i = 0; i < 8; ++i) {
        const int row = m0 + ty * 8 + i;
        if (row >= M) continue;
        const size_t rbase = (size_t)row * N;
#pragma unroll
        for (int g = 0; g < 2; ++g) {
            const int col = n0 + tx * 2 + g * 32;
            if (col + 1 < N) {
                float2 st; st.x = acc[i][g*2+0]; st.y = acc[i][g*2+1];
                *(float2*)(Cout + rbase + col) = st;
            } else if (col < N) {
                Cout[rbase + col] = acc[i][g*2+0];
            }
        }
    }
}

// ---------------------------------------------------------------------------
__global__ void ij_bias_kernel(const float* __restrict__ b_ih, const float* __restrict__ b_hh,
                               float* __restrict__ bias)
{
    int i = blockIdx.x * 256 + threadIdx.x;
    if (i < G4) bias[i] = b_ih[i] + b_hh[i];
}

// emb[r,e] = relu(W_emb[e, pop[r]] + b_emb[e])
__global__ void ij_emb_kernel(const float* __restrict__ W_emb, const float* __restrict__ b_emb,
                              const int* __restrict__ pop_t, float* __restrict__ emb)
{
    int i = blockIdx.x * 256 + threadIdx.x;
    if (i >= BKR * EE) return;
    int r = i >> 7, e = i & 127;
    float v = W_emb[e * DD + pop_t[r]] + b_emb[e];
    emb[i] = v > 0.f ? v : 0.f;
}

// LSTM elementwise; fuses the gate GEMM split-K reduce + xfW row-add + bias.
__global__ void ij_lstm_kernel(const float* __restrict__ z0, const float* __restrict__ z1,
                               const float* __restrict__ xfw, const float* __restrict__ bias,
                               const float* __restrict__ c,
                               float* __restrict__ h2, float* __restrict__ c2)
{
    int i = blockIdx.x * 256 + threadIdx.x;
    if (i >= BKR * HH) return;
    int r = i >> 11, hh = i & 2047;
    const size_t zb = (size_t)r * G4;
    const float* xw = xfw + (size_t)(r & 63) * G4;
    float iv = z0[zb + hh]        + z1[zb + hh]        + xw[hh]        + bias[hh];
    float fv = z0[zb + HH + hh]   + z1[zb + HH + hh]   + xw[HH + hh]   + bias[HH + hh];
    float gv = z0[zb + 2*HH + hh] + z1[zb + 2*HH + hh] + xw[2*HH + hh] + bias[2*HH + hh];
    float ov = z0[zb + 3*HH + hh] + z1[zb + 3*HH + hh] + xw[3*HH + hh] + bias[3*HH + hh];
    float si = 1.f / (1.f + expf(-iv));
    float sf = 1.f / (1.f + expf(-fv));
    float so = 1.f / (1.f + expf(-ov));
    float cv = sf * c[i] + si * tanhf(gv);
    c2[i] = cv;
    h2[i] = so * tanhf(cv);
}

__global__ void ij_reduce_fc1_kernel(const float* __restrict__ part, const float* __restrict__ b_fc1,
                                     float* __restrict__ hd)
{
    int i = blockIdx.x * 256 + threadIdx.x;
    if (i >= BKR * HH) return;
    float v = part[i] + part[i + 1048576] + part[i + 2097152] + part[i + 3145728]
            + b_fc1[i & 2047];
    hd[i] = v > 0.f ? v : 0.f;
}

__global__ void ij_reduce_xfw_kernel(const float* __restrict__ part, float* __restrict__ xfw)
{
    int i = blockIdx.x * 256 + threadIdx.x;
    if (i >= BB * G4) return;
    xfw[i] = part[i] + part[i + 524288] + part[i + 1048576] + part[i + 1572864];
}

// ---------------------------------------------------------------------------
// Per-row (512 blocks): reduce 16 split-K logits partials + b_out + mask row,
// log_softmax, greedy argmax (lowest index on tie), Gumbel-with-max g.
// All in f64 (decision-critical).
// ---------------------------------------------------------------------------
__global__ __launch_bounds__(256)
void ij_softmax_g_kernel(const float* __restrict__ part, const float* __restrict__ b_out,
                         const float* __restrict__ mask_table, const int* __restrict__ pop_t,
                         const float* __restrict__ gum_t, const double* __restrict__ G,
                         const double* __restrict__ logp,
                         double* __restrict__ logp_tok, double* __restrict__ gmat,
                         int* __restrict__ greedy)
{
    const int r = blockIdx.x, tid = threadIdx.x;
    __shared__ double sred[256];
    __shared__ int    sidx[256];
    __shared__ double sbc[2];

    const int pop = pop_t[r];
    const int j0 = tid, j1 = tid + 256;
    double lg0 = -INFINITY, lg1 = -INFINITY;
    if (j0 < DD) {
        double v = (double)b_out[j0] + (double)mask_table[pop * DD + j0];
#pragma unroll
        for (int s = 0; s < 16; ++s) v += (double)part[(size_t)s * (BKR*DD) + (size_t)r * DD + j0];
        lg0 = v;
    }
    if (j1 < DD) {
        double v = (double)b_out[j1] + (double)mask_table[pop * DD + j1];
#pragma unroll
        for (int s = 0; s < 16; ++s) v += (double)part[(size_t)s * (BKR*DD) + (size_t)r * DD + j1];
        lg1 = v;
    }
    double mv = lg0; int mi = j0;
    if (lg1 > mv) { mv = lg1; mi = j1; }
    sred[tid] = mv; sidx[tid] = mi;
    __syncthreads();
    for (int off = 128; off > 0; off >>= 1) {
        if (tid < off) {
            double ov = sred[tid+off]; int oi = sidx[tid+off];
            if (ov > sred[tid] || (ov == sred[tid] && oi < sidx[tid])) { sred[tid] = ov; sidx[tid] = oi; }
        }
        __syncthreads();
    }
    if (tid == 0) { sbc[0] = sred[0]; greedy[r] = sidx[0]; }
    __syncthreads();
    const double rowmax = sbc[0];

    double es = 0.0;
    if (j0 < DD) es += exp(lg0 - rowmax);
    if (j1 < DD) es += exp(lg1 - rowmax);
    __syncthreads();
    sred[tid] = es;
    __syncthreads();
    for (int off = 128; off > 0; off >>= 1) {
        if (tid < off) sred[tid] += sred[tid+off];
        __syncthreads();
    }
    if (tid == 0) sbc[1] = log(sred[0]);
    __syncthreads();
    const double lse = sbc[1];
    const double lpr = logp[r], Gr = G[r];

    double gp0 = -INFINITY, gp1 = -INFINITY;
    if (j0 < DD) {
        double lt = lg0 - rowmax - lse;
        logp_tok[(size_t)r * DD + j0] = lt;
        double u = (double)gum_t[(size_t)r * DD + j0];
        u = fmin(fmax(u, 1e-9), 1.0 - 1e-9);
        gp0 = lt + lpr + (-log(-log(u)));
    }
    if (j1 < DD) {
        double lt = lg1 - rowmax - lse;
        logp_tok[(size_t)r * DD + j1] = lt;
        double u = (double)gum_t[(size_t)r * DD + j1];
        u = fmin(fmax(u, 1e-9), 1.0 - 1e-9);
        gp1 = lt + lpr + (-log(-log(u)));
    }
    __syncthreads();
    sred[tid] = fmax(gp0, gp1);
    __syncthreads();
    for (int off = 128; off > 0; off >>= 1) {
        if (tid < off) sred[tid] = fmax(sred[tid], sred[tid+off]);
        __syncthreads();
    }
    const double Z = sred[0];
    if (j0 < DD) {
        double v = Gr - gp0 + log1p(-exp(gp0 - Z));
        gmat[(size_t)r * DD + j0] = Gr - fmax(v, 0.0) - log1p(exp(-fabs(v)));
    }
    if (j1 < DD) {
        double v = Gr - gp1 + log1p(-exp(gp1 - Z));
        gmat[(size_t)r * DD + j1] = Gr - fmax(v, 0.0) - log1p(exp(-fabs(v)));
    }
}

// ---------------------------------------------------------------------------
// One block per image b. Top-8 of 3200 candidates (desc, low index on tie ==
// jax.lax.top_k), then beam bookkeeping. Rows for image b are {s*64+b}.
// ---------------------------------------------------------------------------
__global__ __launch_bounds__(256)
void ij_beam_kernel(const double* __restrict__ gmat, const double* __restrict__ logp_tok,
                    const int* __restrict__ greedy, const int* __restrict__ pop_t,
                    const float* __restrict__ mask_table,
                    double* __restrict__ G, double* __restrict__ logp,
                    double* __restrict__ samples, double* __restrict__ outs,
                    double* __restrict__ entacc, double* __restrict__ wpq,
                    double* __restrict__ lgp_o, int* __restrict__ order_g, int t)
{
    const int b = blockIdx.x, tid = threadIdx.x;
    __shared__ double sv[256];
    __shared__ int    si2[256];
    __shared__ double gval8[8];
    __shared__ int    gidx8[8];
    __shared__ int    ord8[8], smp8[8];
    __shared__ double lp28[8], sel8[8], Gn8[8];
    __shared__ double oldS[8][TT], oldO[8][TT];
    __shared__ double efull[8];

    if (t > 0) {
        for (int pass = 0; pass < 8; ++pass) {
            double bv = -INFINITY; int bi = 0x7fffffff;
            for (int cand = tid; cand < KK * DD; cand += 256) {
                bool used = false;
                for (int p = 0; p < pass; ++p) used |= (gidx8[p] == cand);
                if (used) continue;
                int kb2 = cand / DD, d = cand - kb2 * DD;
                double v = gmat[(size_t)(kb2 * BB + b) * DD + d];
                if (v > bv || (v == bv && cand < bi)) { bv = v; bi = cand; }
            }
            sv[tid] = bv; si2[tid] = bi;
            __syncthreads();
            for (int off = 128; off > 0; off >>= 1) {
                if (tid < off) {
                    double ov = sv[tid+off]; int oi = si2[tid+off];
                    if (ov > sv[tid] || (ov == sv[tid] && oi < si2[tid])) { sv[tid] = ov; si2[tid] = oi; }
                }
                __syncthreads();
            }
            if (tid == 0) { gval8[pass] = sv[0]; gidx8[pass] = si2[0]; }
            __syncthreads();
        }
    }

    if (tid < 8) {
        const int s = tid, rp = s * BB + b;
        int ord, smp; double Gn;
        if (t == 0) { ord = rp; smp = greedy[rp]; Gn = G[rp]; }
        else {
            int idx = gidx8[s]; int kb2 = idx / DD;
            ord = kb2 * BB + b; smp = idx - kb2 * DD; Gn = gval8[s];
        }
        ord8[s] = ord; smp8[s] = smp; Gn8[s] = Gn;
        double sel = logp_tok[(size_t)ord * DD + smp];
        double lp2 = (t == 0) ? logp[ord] : logp[ord] + sel;
        sel8[s] = sel; lp28[s] = lp2;
    }
    __syncthreads();
    if (tid < 8 * TT) {
        int s = tid / TT, ttc = tid - s * TT;
        oldS[s][ttc] = samples[ord8[s] * TT + ttc];
        oldO[s][ttc] = outs[ord8[s] * TT + ttc];
    }
    __syncthreads();
    if (tid < 8 * TT) {
        int s = tid / TT, ttc = tid - s * TT;
        int rp = s * BB + b;
        samples[rp * TT + ttc] = (ttc == t) ? (double)smp8[s] : oldS[s][ttc];
        outs[rp * TT + ttc]    = (ttc == t) ? sel8[s]         : oldO[s][ttc];
    }
    if (tid >= 96 && tid < 104) {
        int s = tid - 96, rp = s * BB + b;
        G[rp]       = Gn8[s];
        logp[rp]    = lp28[s];
        order_g[rp] = ord8[s];
    }

    if (t > 0) {
        for (int s = 0; s < KK - 1; ++s) {
            const int ord = ord8[s];
            const double* lrow = logp_tok + (size_t)ord * DD;
            const float*  mrow = mask_table + (size_t)pop_t[ord] * DD;
            double acc = 0.0;
            for (int j = tid; j < DD; j += 256) {
                double lp_ = lrow[j];
                if (mrow[j] == 0.0f) acc += lp_ * exp(lp_);
            }
            __syncthreads();
            sv[tid] = acc;
            __syncthreads();
            for (int off = 128; off > 0; off >>= 1) {
                if (tid < off) sv[tid] += sv[tid+off];
                __syncthreads();
            }
            if (tid == 0) efull[s] = sv[0];
            __syncthreads();
        }
        if (tid == 0) {
            const double gk = gval8[7];
            double sw = 0.0, swe = 0.0;
            for (int s = 0; s < KK - 1; ++s) {
                double phi = lp28[s];
                double x = gk - phi;
                double y = exp(-x);
                double gls;
                if (x >= 10.0) gls = -x - y * 0.5 + y * y * (1.0 / 24.0);
                else           gls = log(-expm1(-exp(-fmin(x, 10.0))));
                double w = exp(phi - gls);
                wpq[b * (KK-1) + s]   = w;
                lgp_o[b * (KK-1) + s] = phi;
                sw += w; swe += w * efull[s];
            }
            entacc[b] += swe / sw;
        }
    }
}

__global__ void ij_permute_kernel(const float* __restrict__ h2, const float* __restrict__ c2,
                                  const int* __restrict__ order_g,
                                  float* __restrict__ h, float* __restrict__ c)
{
    int i = blockIdx.x * 256 + threadIdx.x;
    if (i >= BKR * HH) return;
    int r = i >> 11, j = i & 2047;
    int o = order_g[r];
    h[i] = h2[(size_t)o * HH + j];
    c[i] = c2[(size_t)o * HH + j];
}

__global__ void ij_final_kernel(const double* __restrict__ outs, const double* __restrict__ samples,
                                const double* __restrict__ entacc, const double* __restrict__ wpq,
                                const double* __restrict__ lgp_o, float* __restrict__ out)
{
    int i = blockIdx.x * 256 + threadIdx.x;
    if (i < 5376) {
        int bb = i / 84, rest = i - bb * 84;
        int s = rest / TT, ttc = rest - s * TT;
        size_t src = (size_t)(s * BB + bb) * TT + ttc;
        out[i]        = (float)outs[src];
        out[5376 + i] = (float)samples[src];
    } else if (i < 5440) {
        out[10752 + (i - 5376)] = (float)entacc[i - 5376];
    } else if (i < 5888) {
        int q = i - 5440; out[10816 + q] = (float)wpq[q];
    } else if (i < 6336) {
        int q = i - 5888; out[11264 + q] = (float)lgp_o[q];
    }
}

// ---------------------------------------------------------------------------
extern "C" void kernel_launch(void* const* d_in, const int* in_sizes, int n_in,
                              void* d_out, int out_size, void* d_ws, size_t ws_size,
                              hipStream_t stream)
{
    const float* x_f   = (const float*)d_in[0];
    const float* x_f3  = (const float*)d_in[1];
    const float* gum   = (const float*)d_in[2];
    const int*   pop   = (const int*)d_in[3];
    const float* mask  = (const float*)d_in[4];
    const float* W_emb = (const float*)d_in[5];
    const float* b_emb = (const float*)d_in[6];
    const float* W_ih  = (const float*)d_in[7];
    const float* W_hh  = (const float*)d_in[8];
    const float* b_ih  = (const float*)d_in[9];
    const float* b_hh  = (const float*)d_in[10];
    const float* W_fc1 = (const float*)d_in[11];
    const float* b_fc1 = (const float*)d_in[12];
    const float* W_out = (const float*)d_in[13];
    const float* b_out = (const float*)d_in[14];
    float* out = (float*)d_out;
    char*  ws  = (char*)d_ws;

    if (ws_size < WS_TOTAL) return;

    double* STATE = (double*)(ws + OFF_STATE);
    double* Gv    = STATE + SI_G;
    double* LOGP  = STATE + SI_LOGP;
    double* SAMP  = STATE + SI_SAMP;
    double* OUTS  = STATE + SI_OUTS;
    double* ENT   = STATE + SI_ENT;
    double* WPQ   = STATE + SI_WPQ;
    double* LGP   = STATE + SI_LGP;
    float*  H     = (float*)(ws + OFF_H);
    float*  Cc    = (float*)(ws + OFF_C);
    float*  Z     = (float*)(ws + OFF_Z);
    float*  Z1    = Z + (size_t)BKR * G4;      // second gate split-K partial
    float*  H2    = (float*)(ws + OFF_H2);
    float*  C2    = (float*)(ws + OFF_C2);
    float*  HD    = (float*)(ws + OFF_HD);
    float*  EMB   = (float*)(ws + OFF_EMB);
    float*  XFW   = (float*)(ws + OFF_XFW);
    float*  BIAS  = (float*)(ws + OFF_BIAS);
    double* LPT   = (double*)(ws + OFF_LPT);
    double* GMAT  = (double*)(ws + OFF_GMAT);
    int*    ORDER = (int*)(ws + OFF_INTS);
    int*    GREEDY= ORDER + 512;

    // zero f64 state + h + c
    hipMemsetAsync(ws, 0, ZERO_END, stream);
    ij_bias_kernel<<<32, 256, 0, stream>>>(b_ih, b_hh, BIAS);

    // xfW = x_f @ W_ih[:, :2048]^T   (split-K=4 partials into Z, reduce)
    ij_gemm_f32<<<dim3(128, 1, 4), 256, 0, stream>>>(
        x_f, nullptr, nullptr, 1 << 30, 1 << 30, 2048, 0, 0,
        W_ih, nullptr, 1 << 30, 4224, 0,
        Z, BB, G4, 512);
    ij_reduce_xfw_kernel<<<2048, 256, 0, stream>>>(Z, XFW);

    for (int t = 0; t < TT; ++t) {
        const int* pop_t = pop + t * BKR;
        ij_emb_kernel<<<256, 256, 0, stream>>>(W_emb, b_emb, pop_t, EMB);

        // gate GEMM: A = [emb | xf3_t | h], B = [W_ih cols 2048.. | W_hh]
        // split-K=2 partials; lstm kernel fuses reduce + xfW + bias.
        ij_gemm_f32<<<dim3(128, 4, 2), 256, 0, stream>>>(
            EMB, x_f3 + (size_t)t * BKR * 2048, H, 128, 2176, 128, 2048, 2048,
            W_ih + 2048, W_hh, 2176, 4224, 2048,
            Z, BKR, G4, 2112);

        ij_lstm_kernel<<<4096, 256, 0, stream>>>(Z, Z1, XFW, BIAS, Cc, H2, C2);

        // fc1 (split-K=4 into Z, reduce w/ bias+relu)
        ij_gemm_f32<<<dim3(32, 4, 4), 256, 0, stream>>>(
            H2, nullptr, nullptr, 1 << 30, 1 << 30, 2048, 0, 0,
            W_fc1, nullptr, 1 << 30, 2048, 0,
            Z, BKR, HH, 512);
        ij_reduce_fc1_kernel<<<4096, 256, 0, stream>>>(Z, b_fc1, HD);

        // logits (split-K=16 into Z; reduce folded into softmax kernel)
        ij_gemm_f32<<<dim3(7, 4, 16), 256, 0, stream>>>(
            HD, nullptr, nullptr, 1 << 30, 1 << 30, 2048, 0, 0,
            W_out, nullptr, 1 << 30, 2048, 0,
            Z, BKR, DD, 128);

        ij_softmax_g_kernel<<<512, 256, 0, stream>>>(
            Z, b_out, mask, pop_t, gum + (size_t)t * BKR * DD,
            Gv, LOGP, LPT, GMAT, GREEDY);

        ij_beam_kernel<<<64, 256, 0, stream>>>(
            GMAT, LPT, GREEDY, pop_t, mask,
            Gv, LOGP, SAMP, OUTS, ENT, WPQ, LGP, ORDER, t);

        ij_permute_kernel<<<4096, 256, 0, stream>>>(H2, C2, ORDER, H, Cc);
    }

    ij_final_kernel<<<25, 256, 0, stream>>>(OUTS, SAMP, ENT, WPQ, LGP, out);
    (void)in_sizes; (void)n_in; (void)out_size;
}

// Round 3
// 3704.581 us; speedup vs baseline: 6.3327x; 2.6227x over previous
//
#include <hip/hip_runtime.h>
#include <math.h>

// ---------------------------------------------------------------------------
// ImitateJoint: 12-step beam-search LSTM decoder.
// B=64 images, K=8 beams (BK=512 rows), T=12, H=2048, IN=2048, D=400, E=128.
// Round 3: GEMMs on the matrix pipe via f16-split (hi + 2^-11*lo') with dual
// fp32 MFMA accumulators -> ~fp32 accuracy at ~650 TF f32-equiv peak.
// Decision-critical math (softmax, Gumbel g, top-k, entropy) stays fp64.
// ---------------------------------------------------------------------------

#define BB   64
#define KK   8
#define TT   12
#define HH   2048
#define DD   400
#define EE   128
#define BKR  512          // B*K rows
#define G4   8192         // 4*H

// ---- workspace layout (byte offsets) --------------------------------------
static const size_t OFF_STATE = 0;                // doubles, 14272 used
static const size_t OFF_H     = 114688;           // float [512][2048]
static const size_t OFF_C     = 4308992;          // float [512][2048]
static const size_t ZERO_END  = 8503296;          // memset 0 .. here
static const size_t OFF_Z     = 8503296;          // float, 2*512*8192 partials
static const size_t OFF_H2    = 42057728;         // float [512][2048]
static const size_t OFF_C2    = 46252032;         // float [512][2048]
static const size_t OFF_HD    = 50446336;         // float [512][2048]
static const size_t OFF_EMB   = 54640640;         // float [512][128]
static const size_t OFF_XFW   = 54902784;         // float [64][8192]
static const size_t OFF_BIAS  = 56999936;         // float [8192]
static const size_t OFF_LPT   = 57032704;         // double [512][400]
static const size_t OFF_GMAT  = 58671104;         // double [512][400]
static const size_t OFF_INTS  = 60309504;         // int [1024]
static const size_t WS_TOTAL  = 60313600;         // ~57.5 MB

#define SI_G    0
#define SI_LOGP 512
#define SI_SAMP 1024
#define SI_OUTS 7168
#define SI_ENT  13312
#define SI_WPQ  13376
#define SI_LGP  13824

using half8  = __attribute__((ext_vector_type(8))) _Float16;
using floatx4 = __attribute__((ext_vector_type(4))) float;

// ---------------------------------------------------------------------------
// MFMA f16-split GEMM: C[z][512][N] = A[512,K]*B[N,K]^T partials.
// Block 256 thr = 4 waves; block tile 128x128; wave tile 64x64 = 4x4 of
// 16x16x32 MFMA; K-chunks of 32. LDS: hi/lo planes in fragment-linear order
// (slot swizzle: conflict-free reads, <=2-way writes). Register-prefetch of
// next chunk's globals overlaps VMEM latency with MFMA.
// z = acc1 + acc2/2048, acc1 = hi*hi, acc2 = hi*lo' + lo'*hi, lo' = 2048*lo.
// A: up to 3 concatenated f32 segments; B: up to 2 (weights are N-major).
// ---------------------------------------------------------------------------
__global__ __launch_bounds__(256, 2)
void ij_gemm_f16x3(const float* __restrict__ A0, const float* __restrict__ A1,
                   const float* __restrict__ A2, int kA1, int kA2,
                   int lda0, int lda1, int lda2,
                   const float* __restrict__ B0, const float* __restrict__ B1,
                   int kB1, int ldb0, int ldb1,
                   float* __restrict__ C, int N, int Klen)
{
    // 32 KB: A_hi[512] A_lo[512] B_hi[512] B_lo[512] half8-chunks
    __shared__ half8 lds[2048];

    const int tid = threadIdx.x;
    const int n0  = blockIdx.x * 128;
    const int m0  = blockIdx.y * 128;
    const int kstart = blockIdx.z * Klen;
    const int nch = Klen / 32;
    float* Cout = C + (size_t)blockIdx.z * ((size_t)512 * (size_t)N);

    const int wid    = tid >> 6;
    const int wave_m = wid & 1;          // 0..1
    const int wave_n = wid >> 1;         // 0..1
    const int lane   = tid & 63;
    const int lo16   = lane & 15;        // m/n within 16-tile (and C col)
    const int oq     = lane >> 4;        // k-octet (and C row quad)
    const int laneSlot = oq * 16 + ((lo16 + 4 * oq) & 15);   // swizzled chunk

    // staging assignment: unit u = i*256+tid; row=u>>2 (0..127), o=u&3
    const int st_o   = tid & 3;
    const int st_row0 = tid >> 2;        // +64*i
    const int st_slot = ((st_row0 & 15) + 4 * st_o) & 15;    // r part; +o*16

    float4 pfA[2][2], pfB[2][2];

    auto loadGlobals = [&](int c) {
        const int kb = kstart + c * 32;
#pragma unroll
        for (int i = 0; i < 2; ++i) {
            const int row = st_row0 + i * 64;
            const int kc  = kb + st_o * 8;
            const float* ap; int ao, ld;
            if (kc < kA1)      { ap = A0; ao = kc;       ld = lda0; }
            else if (kc < kA2) { ap = A1; ao = kc - kA1; ld = lda1; }
            else               { ap = A2; ao = kc - kA2; ld = lda2; }
            const float* p = ap + (size_t)(m0 + row) * ld + ao;
            pfA[i][0] = *(const float4*)(p);
            pfA[i][1] = *(const float4*)(p + 4);
            const int bn = n0 + row;
            const float* bp; int bo, bld;
            if (kc < kB1) { bp = B0; bo = kc;       bld = ldb0; }
            else          { bp = B1; bo = kc - kB1; bld = ldb1; }
            if (bn < N) {
                const float* q = bp + (size_t)bn * bld + bo;
                pfB[i][0] = *(const float4*)(q);
                pfB[i][1] = *(const float4*)(q + 4);
            } else {
                pfB[i][0] = make_float4(0.f,0.f,0.f,0.f);
                pfB[i][1] = make_float4(0.f,0.f,0.f,0.f);
            }
        }
    };

    auto writeLDS = [&]() {
#pragma unroll
        for (int i = 0; i < 2; ++i) {
            const int row = st_row0 + i * 64;
            const int mt  = row >> 4;
            const int idx = mt * 64 + st_o * 16 + (((row & 15) + 4 * st_o) & 15);
            // A
            {
                float x[8] = {pfA[i][0].x, pfA[i][0].y, pfA[i][0].z, pfA[i][0].w,
                              pfA[i][1].x, pfA[i][1].y, pfA[i][1].z, pfA[i][1].w};
                half8 hi8, lo8;
#pragma unroll
                for (int j = 0; j < 8; ++j) {
                    _Float16 h = (_Float16)x[j];
                    hi8[j] = h;
                    lo8[j] = (_Float16)((x[j] - (float)h) * 2048.0f);
                }
                lds[idx]       = hi8;
                lds[512 + idx] = lo8;
            }
            // B
            {
                float x[8] = {pfB[i][0].x, pfB[i][0].y, pfB[i][0].z, pfB[i][0].w,
                              pfB[i][1].x, pfB[i][1].y, pfB[i][1].z, pfB[i][1].w};
                half8 hi8, lo8;
#pragma unroll
                for (int j = 0; j < 8; ++j) {
                    _Float16 h = (_Float16)x[j];
                    hi8[j] = h;
                    lo8[j] = (_Float16)((x[j] - (float)h) * 2048.0f);
                }
                lds[1024 + idx] = hi8;
                lds[1536 + idx] = lo8;
            }
        }
    };

    floatx4 acc1[4][4], acc2[4][4];
#pragma unroll
    for (int i = 0; i < 4; ++i)
#pragma unroll
        for (int j = 0; j < 4; ++j) { acc1[i][j] = (floatx4)0.f; acc2[i][j] = (floatx4)0.f; }

    loadGlobals(0);
    for (int c = 0; c < nch; ++c) {
        __syncthreads();               // prior chunk's fragment reads complete
        writeLDS();
        __syncthreads();
        if (c + 1 < nch) loadGlobals(c + 1);

        half8 Ahi[4], Alo[4];
#pragma unroll
        for (int mt = 0; mt < 4; ++mt) {
            const int amt = wave_m * 4 + mt;
            Ahi[mt] = lds[amt * 64 + laneSlot];
            Alo[mt] = lds[512 + amt * 64 + laneSlot];
        }
#pragma unroll
        for (int nt = 0; nt < 4; ++nt) {
            const int bnt = wave_n * 4 + nt;
            half8 Bhi = lds[1024 + bnt * 64 + laneSlot];
            half8 Blo = lds[1536 + bnt * 64 + laneSlot];
#pragma unroll
            for (int mt = 0; mt < 4; ++mt) {
                acc1[mt][nt] = __builtin_amdgcn_mfma_f32_16x16x32_f16(Ahi[mt], Bhi, acc1[mt][nt], 0, 0, 0);
                acc2[mt][nt] = __builtin_amdgcn_mfma_f32_16x16x32_f16(Ahi[mt], Blo, acc2[mt][nt], 0, 0, 0);
                acc2[mt][nt] = __builtin_amdgcn_mfma_f32_16x16x32_f16(Alo[mt], Bhi, acc2[mt][nt], 0, 0, 0);
            }
        }
    }

    // epilogue: C row = m0+wave_m*64+mt*16+oq*4+v, col = n0+wave_n*64+nt*16+lo16
    const float s = 1.0f / 2048.0f;
#pragma unroll
    for (int mt = 0; mt < 4; ++mt) {
        const int rbase = m0 + wave_m * 64 + mt * 16 + oq * 4;
#pragma unroll
        for (int nt = 0; nt < 4; ++nt) {
            const int col = n0 + wave_n * 64 + nt * 16 + lo16;
            if (col >= N) continue;
#pragma unroll
            for (int v = 0; v < 4; ++v) {
                float val = acc1[mt][nt][v] + acc2[mt][nt][v] * s;
                Cout[(size_t)(rbase + v) * N + col] = val;
            }
        }
    }
}

// ---------------------------------------------------------------------------
// fp32 vector GEMM (kept for the one-time xfW precompute, M=64).
// ---------------------------------------------------------------------------
#define FBM 128
#define FBN 64
#define FBK 16

__global__ __launch_bounds__(256, 2)
void ij_gemm_f32(const float* __restrict__ A0, const float* __restrict__ A1,
                 const float* __restrict__ A2, int kA1, int kA2,
                 int lda0, int lda1, int lda2,
                 const float* __restrict__ B0, const float* __restrict__ B1,
                 int kB1, int ldb0, int ldb1,
                 float* __restrict__ C, int M, int N, int Klen)
{
    __shared__ float As[2][FBK][FBM];
    __shared__ float Bs[2][FBK][FBN];

    const int tid = threadIdx.x;
    const int tx  = tid & 15;
    const int ty  = tid >> 4;
    const int n0  = blockIdx.x * FBN;
    const int m0  = blockIdx.y * FBM;
    const int kstart = blockIdx.z * Klen;
    const int nch = Klen / FBK;
    float* Cout = C + (size_t)blockIdx.z * ((size_t)M * (size_t)N);

    const int srow = tid >> 2;
    const int kq   = tid & 3;

    float4 aR0, aR1, bR;

    auto loadChunk = [&](int kb0) {
        const int kc = kb0 + kq * 4;
        const float* ap; int ao, ld;
        if (kc < kA1)      { ap = A0; ao = kc;       ld = lda0; }
        else if (kc < kA2) { ap = A1; ao = kc - kA1; ld = lda1; }
        else               { ap = A2; ao = kc - kA2; ld = lda2; }
        const int r0 = m0 + srow, r1 = r0 + 64;
        aR0 = (r0 < M) ? *(const float4*)(ap + (size_t)r0 * ld + ao)
                       : make_float4(0.f, 0.f, 0.f, 0.f);
        aR1 = (r1 < M) ? *(const float4*)(ap + (size_t)r1 * ld + ao)
                       : make_float4(0.f, 0.f, 0.f, 0.f);
        const float* bp; int bo, bld;
        if (kc < kB1) { bp = B0; bo = kc;       bld = ldb0; }
        else          { bp = B1; bo = kc - kB1; bld = ldb1; }
        const int bn = n0 + srow;
        bR = (bn < N) ? *(const float4*)(bp + (size_t)bn * bld + bo)
                      : make_float4(0.f, 0.f, 0.f, 0.f);
    };
    auto storeChunk = [&](int bsel) {
        const int k4 = kq * 4;
        As[bsel][k4+0][srow]      = aR0.x;
        As[bsel][k4+1][srow]      = aR0.y;
        As[bsel][k4+2][srow]      = aR0.z;
        As[bsel][k4+3][srow]      = aR0.w;
        As[bsel][k4+0][srow + 64] = aR1.x;
        As[bsel][k4+1][srow + 64] = aR1.y;
        As[bsel][k4+2][srow + 64] = aR1.z;
        As[bsel][k4+3][srow + 64] = aR1.w;
        Bs[bsel][k4+0][srow]      = bR.x;
        Bs[bsel][k4+1][srow]      = bR.y;
        Bs[bsel][k4+2][srow]      = bR.z;
        Bs[bsel][k4+3][srow]      = bR.w;
    };

    float acc[8][4];
#pragma unroll
    for (int i = 0; i < 8; ++i)
#pragma unroll
        for (int j = 0; j < 4; ++j) acc[i][j] = 0.f;

    loadChunk(kstart);
    storeChunk(0);
    __syncthreads();
    int bsel = 0;
    for (int c = 0; c < nch; ++c) {
        if (c + 1 < nch) loadChunk(kstart + (c + 1) * FBK);
#pragma unroll
        for (int kkk = 0; kkk < FBK; ++kkk) {
            float a[8], b[4];
            const float4 av0 = *(const float4*)&As[bsel][kkk][ty * 8];
            const float4 av1 = *(const float4*)&As[bsel][kkk][ty * 8 + 4];
            a[0]=av0.x; a[1]=av0.y; a[2]=av0.z; a[3]=av0.w;
            a[4]=av1.x; a[5]=av1.y; a[6]=av1.z; a[7]=av1.w;
            const float2 bv0 = *(const float2*)&Bs[bsel][kkk][tx * 2];
            const float2 bv1 = *(const float2*)&Bs[bsel][kkk][tx * 2 + 32];
            b[0]=bv0.x; b[1]=bv0.y; b[2]=bv1.x; b[3]=bv1.y;
#pragma unroll
            for (int i = 0; i < 8; ++i)
#pragma unroll
                for (int j = 0; j < 4; ++j)
                    acc[i][j] = fmaf(a[i], b[j], acc[i][j]);
        }
        if (c + 1 < nch) storeChunk(bsel ^ 1);
        __syncthreads();
        bsel ^= 1;
    }

#pragma unroll
    for (int i = 0; i < 8; ++i) {
        const int row = m0 + ty * 8 + i;
        if (row >= M) continue;
        const size_t rbase = (size_t)row * N;
#pragma unroll
        for (int g = 0; g < 2; ++g) {
            const int col = n0 + tx * 2 + g * 32;
            if (col + 1 < N) {
                float2 st; st.x = acc[i][g*2+0]; st.y = acc[i][g*2+1];
                *(float2*)(Cout + rbase + col) = st;
            } else if (col < N) {
                Cout[rbase + col] = acc[i][g*2+0];
            }
        }
    }
}

// ---------------------------------------------------------------------------
__global__ void ij_bias_kernel(const float* __restrict__ b_ih, const float* __restrict__ b_hh,
                               float* __restrict__ bias)
{
    int i = blockIdx.x * 256 + threadIdx.x;
    if (i < G4) bias[i] = b_ih[i] + b_hh[i];
}

__global__ void ij_emb_kernel(const float* __restrict__ W_emb, const float* __restrict__ b_emb,
                              const int* __restrict__ pop_t, float* __restrict__ emb)
{
    int i = blockIdx.x * 256 + threadIdx.x;
    if (i >= BKR * EE) return;
    int r = i >> 7, e = i & 127;
    float v = W_emb[e * DD + pop_t[r]] + b_emb[e];
    emb[i] = v > 0.f ? v : 0.f;
}

// LSTM elementwise; fuses gate split-K reduce + xfW row-add + bias.
__global__ void ij_lstm_kernel(const float* __restrict__ z0, const float* __restrict__ z1,
                               const float* __restrict__ xfw, const float* __restrict__ bias,
                               const float* __restrict__ c,
                               float* __restrict__ h2, float* __restrict__ c2)
{
    int i = blockIdx.x * 256 + threadIdx.x;
    if (i >= BKR * HH) return;
    int r = i >> 11, hh = i & 2047;
    const size_t zb = (size_t)r * G4;
    const float* xw = xfw + (size_t)(r & 63) * G4;
    float iv = z0[zb + hh]        + z1[zb + hh]        + xw[hh]        + bias[hh];
    float fv = z0[zb + HH + hh]   + z1[zb + HH + hh]   + xw[HH + hh]   + bias[HH + hh];
    float gv = z0[zb + 2*HH + hh] + z1[zb + 2*HH + hh] + xw[2*HH + hh] + bias[2*HH + hh];
    float ov = z0[zb + 3*HH + hh] + z1[zb + 3*HH + hh] + xw[3*HH + hh] + bias[3*HH + hh];
    float si = 1.f / (1.f + expf(-iv));
    float sf = 1.f / (1.f + expf(-fv));
    float so = 1.f / (1.f + expf(-ov));
    float cv = sf * c[i] + si * tanhf(gv);
    c2[i] = cv;
    h2[i] = so * tanhf(cv);
}

__global__ void ij_reduce_fc1_kernel(const float* __restrict__ part, const float* __restrict__ b_fc1,
                                     float* __restrict__ hd)
{
    int i = blockIdx.x * 256 + threadIdx.x;
    if (i >= BKR * HH) return;
    float v = part[i] + part[i + 1048576] + part[i + 2097152] + part[i + 3145728]
            + b_fc1[i & 2047];
    hd[i] = v > 0.f ? v : 0.f;
}

__global__ void ij_reduce_xfw_kernel(const float* __restrict__ part, float* __restrict__ xfw)
{
    int i = blockIdx.x * 256 + threadIdx.x;
    if (i >= BB * G4) return;
    xfw[i] = part[i] + part[i + 524288] + part[i + 1048576] + part[i + 1572864];
}

// ---------------------------------------------------------------------------
// Per-row: reduce 16 logits partials + b_out + mask row, log_softmax, greedy
// argmax, Gumbel-with-max conditioned g. All f64 (decision-critical).
// ---------------------------------------------------------------------------
__global__ __launch_bounds__(256)
void ij_softmax_g_kernel(const float* __restrict__ part, const float* __restrict__ b_out,
                         const float* __restrict__ mask_table, const int* __restrict__ pop_t,
                         const float* __restrict__ gum_t, const double* __restrict__ G,
                         const double* __restrict__ logp,
                         double* __restrict__ logp_tok, double* __restrict__ gmat,
                         int* __restrict__ greedy)
{
    const int r = blockIdx.x, tid = threadIdx.x;
    __shared__ double sred[256];
    __shared__ int    sidx[256];
    __shared__ double sbc[2];

    const int pop = pop_t[r];
    const int j0 = tid, j1 = tid + 256;
    double lg0 = -INFINITY, lg1 = -INFINITY;
    if (j0 < DD) {
        double v = (double)b_out[j0] + (double)mask_table[pop * DD + j0];
#pragma unroll
        for (int s = 0; s < 16; ++s) v += (double)part[(size_t)s * (BKR*DD) + (size_t)r * DD + j0];
        lg0 = v;
    }
    if (j1 < DD) {
        double v = (double)b_out[j1] + (double)mask_table[pop * DD + j1];
#pragma unroll
        for (int s = 0; s < 16; ++s) v += (double)part[(size_t)s * (BKR*DD) + (size_t)r * DD + j1];
        lg1 = v;
    }
    double mv = lg0; int mi = j0;
    if (lg1 > mv) { mv = lg1; mi = j1; }
    sred[tid] = mv; sidx[tid] = mi;
    __syncthreads();
    for (int off = 128; off > 0; off >>= 1) {
        if (tid < off) {
            double ov = sred[tid+off]; int oi = sidx[tid+off];
            if (ov > sred[tid] || (ov == sred[tid] && oi < sidx[tid])) { sred[tid] = ov; sidx[tid] = oi; }
        }
        __syncthreads();
    }
    if (tid == 0) { sbc[0] = sred[0]; greedy[r] = sidx[0]; }
    __syncthreads();
    const double rowmax = sbc[0];

    double es = 0.0;
    if (j0 < DD) es += exp(lg0 - rowmax);
    if (j1 < DD) es += exp(lg1 - rowmax);
    __syncthreads();
    sred[tid] = es;
    __syncthreads();
    for (int off = 128; off > 0; off >>= 1) {
        if (tid < off) sred[tid] += sred[tid+off];
        __syncthreads();
    }
    if (tid == 0) sbc[1] = log(sred[0]);
    __syncthreads();
    const double lse = sbc[1];
    const double lpr = logp[r], Gr = G[r];

    double gp0 = -INFINITY, gp1 = -INFINITY;
    if (j0 < DD) {
        double lt = lg0 - rowmax - lse;
        logp_tok[(size_t)r * DD + j0] = lt;
        double u = (double)gum_t[(size_t)r * DD + j0];
        u = fmin(fmax(u, 1e-9), 1.0 - 1e-9);
        gp0 = lt + lpr + (-log(-log(u)));
    }
    if (j1 < DD) {
        double lt = lg1 - rowmax - lse;
        logp_tok[(size_t)r * DD + j1] = lt;
        double u = (double)gum_t[(size_t)r * DD + j1];
        u = fmin(fmax(u, 1e-9), 1.0 - 1e-9);
        gp1 = lt + lpr + (-log(-log(u)));
    }
    __syncthreads();
    sred[tid] = fmax(gp0, gp1);
    __syncthreads();
    for (int off = 128; off > 0; off >>= 1) {
        if (tid < off) sred[tid] = fmax(sred[tid], sred[tid+off]);
        __syncthreads();
    }
    const double Z = sred[0];
    if (j0 < DD) {
        double v = Gr - gp0 + log1p(-exp(gp0 - Z));
        gmat[(size_t)r * DD + j0] = Gr - fmax(v, 0.0) - log1p(exp(-fabs(v)));
    }
    if (j1 < DD) {
        double v = Gr - gp1 + log1p(-exp(gp1 - Z));
        gmat[(size_t)r * DD + j1] = Gr - fmax(v, 0.0) - log1p(exp(-fabs(v)));
    }
}

// ---------------------------------------------------------------------------
// One block per image b: top-8 of 3200 (desc, low index on tie), bookkeeping.
// ---------------------------------------------------------------------------
__global__ __launch_bounds__(256)
void ij_beam_kernel(const double* __restrict__ gmat, const double* __restrict__ logp_tok,
                    const int* __restrict__ greedy, const int* __restrict__ pop_t,
                    const float* __restrict__ mask_table,
                    double* __restrict__ G, double* __restrict__ logp,
                    double* __restrict__ samples, double* __restrict__ outs,
                    double* __restrict__ entacc, double* __restrict__ wpq,
                    double* __restrict__ lgp_o, int* __restrict__ order_g, int t)
{
    const int b = blockIdx.x, tid = threadIdx.x;
    __shared__ double sv[256];
    __shared__ int    si2[256];
    __shared__ double gval8[8];
    __shared__ int    gidx8[8];
    __shared__ int    ord8[8], smp8[8];
    __shared__ double lp28[8], sel8[8], Gn8[8];
    __shared__ double oldS[8][TT], oldO[8][TT];
    __shared__ double efull[8];

    if (t > 0) {
        for (int pass = 0; pass < 8; ++pass) {
            double bv = -INFINITY; int bi = 0x7fffffff;
            for (int cand = tid; cand < KK * DD; cand += 256) {
                bool used = false;
                for (int p = 0; p < pass; ++p) used |= (gidx8[p] == cand);
                if (used) continue;
                int kb2 = cand / DD, d = cand - kb2 * DD;
                double v = gmat[(size_t)(kb2 * BB + b) * DD + d];
                if (v > bv || (v == bv && cand < bi)) { bv = v; bi = cand; }
            }
            sv[tid] = bv; si2[tid] = bi;
            __syncthreads();
            for (int off = 128; off > 0; off >>= 1) {
                if (tid < off) {
                    double ov = sv[tid+off]; int oi = si2[tid+off];
                    if (ov > sv[tid] || (ov == sv[tid] && oi < si2[tid])) { sv[tid] = ov; si2[tid] = oi; }
                }
                __syncthreads();
            }
            if (tid == 0) { gval8[pass] = sv[0]; gidx8[pass] = si2[0]; }
            __syncthreads();
        }
    }

    if (tid < 8) {
        const int s = tid, rp = s * BB + b;
        int ord, smp; double Gn;
        if (t == 0) { ord = rp; smp = greedy[rp]; Gn = G[rp]; }
        else {
            int idx = gidx8[s]; int kb2 = idx / DD;
            ord = kb2 * BB + b; smp = idx - kb2 * DD; Gn = gval8[s];
        }
        ord8[s] = ord; smp8[s] = smp; Gn8[s] = Gn;
        double sel = logp_tok[(size_t)ord * DD + smp];
        double lp2 = (t == 0) ? logp[ord] : logp[ord] + sel;
        sel8[s] = sel; lp28[s] = lp2;
    }
    __syncthreads();
    if (tid < 8 * TT) {
        int s = tid / TT, ttc = tid - s * TT;
        oldS[s][ttc] = samples[ord8[s] * TT + ttc];
        oldO[s][ttc] = outs[ord8[s] * TT + ttc];
    }
    __syncthreads();
    if (tid < 8 * TT) {
        int s = tid / TT, ttc = tid - s * TT;
        int rp = s * BB + b;
        samples[rp * TT + ttc] = (ttc == t) ? (double)smp8[s] : oldS[s][ttc];
        outs[rp * TT + ttc]    = (ttc == t) ? sel8[s]         : oldO[s][ttc];
    }
    if (tid >= 96 && tid < 104) {
        int s = tid - 96, rp = s * BB + b;
        G[rp]       = Gn8[s];
        logp[rp]    = lp28[s];
        order_g[rp] = ord8[s];
    }

    if (t > 0) {
        for (int s = 0; s < KK - 1; ++s) {
            const int ord = ord8[s];
            const double* lrow = logp_tok + (size_t)ord * DD;
            const float*  mrow = mask_table + (size_t)pop_t[ord] * DD;
            double acc = 0.0;
            for (int j = tid; j < DD; j += 256) {
                double lp_ = lrow[j];
                if (mrow[j] == 0.0f) acc += lp_ * exp(lp_);
            }
            __syncthreads();
            sv[tid] = acc;
            __syncthreads();
            for (int off = 128; off > 0; off >>= 1) {
                if (tid < off) sv[tid] += sv[tid+off];
                __syncthreads();
            }
            if (tid == 0) efull[s] = sv[0];
            __syncthreads();
        }
        if (tid == 0) {
            const double gk = gval8[7];
            double sw = 0.0, swe = 0.0;
            for (int s = 0; s < KK - 1; ++s) {
                double phi = lp28[s];
                double x = gk - phi;
                double y = exp(-x);
                double gls;
                if (x >= 10.0) gls = -x - y * 0.5 + y * y * (1.0 / 24.0);
                else           gls = log(-expm1(-exp(-fmin(x, 10.0))));
                double w = exp(phi - gls);
                wpq[b * (KK-1) + s]   = w;
                lgp_o[b * (KK-1) + s] = phi;
                sw += w; swe += w * efull[s];
            }
            entacc[b] += swe / sw;
        }
    }
}

__global__ void ij_permute_kernel(const float* __restrict__ h2, const float* __restrict__ c2,
                                  const int* __restrict__ order_g,
                                  float* __restrict__ h, float* __restrict__ c)
{
    int i = blockIdx.x * 256 + threadIdx.x;
    if (i >= BKR * HH) return;
    int r = i >> 11, j = i & 2047;
    int o = order_g[r];
    h[i] = h2[(size_t)o * HH + j];
    c[i] = c2[(size_t)o * HH + j];
}

__global__ void ij_final_kernel(const double* __restrict__ outs, const double* __restrict__ samples,
                                const double* __restrict__ entacc, const double* __restrict__ wpq,
                                const double* __restrict__ lgp_o, float* __restrict__ out)
{
    int i = blockIdx.x * 256 + threadIdx.x;
    if (i < 5376) {
        int bb = i / 84, rest = i - bb * 84;
        int s = rest / TT, ttc = rest - s * TT;
        size_t src = (size_t)(s * BB + bb) * TT + ttc;
        out[i]        = (float)outs[src];
        out[5376 + i] = (float)samples[src];
    } else if (i < 5440) {
        out[10752 + (i - 5376)] = (float)entacc[i - 5376];
    } else if (i < 5888) {
        int q = i - 5440; out[10816 + q] = (float)wpq[q];
    } else if (i < 6336) {
        int q = i - 5888; out[11264 + q] = (float)lgp_o[q];
    }
}

// ---------------------------------------------------------------------------
extern "C" void kernel_launch(void* const* d_in, const int* in_sizes, int n_in,
                              void* d_out, int out_size, void* d_ws, size_t ws_size,
                              hipStream_t stream)
{
    const float* x_f   = (const float*)d_in[0];
    const float* x_f3  = (const float*)d_in[1];
    const float* gum   = (const float*)d_in[2];
    const int*   pop   = (const int*)d_in[3];
    const float* mask  = (const float*)d_in[4];
    const float* W_emb = (const float*)d_in[5];
    const float* b_emb = (const float*)d_in[6];
    const float* W_ih  = (const float*)d_in[7];
    const float* W_hh  = (const float*)d_in[8];
    const float* b_ih  = (const float*)d_in[9];
    const float* b_hh  = (const float*)d_in[10];
    const float* W_fc1 = (const float*)d_in[11];
    const float* b_fc1 = (const float*)d_in[12];
    const float* W_out = (const float*)d_in[13];
    const float* b_out = (const float*)d_in[14];
    float* out = (float*)d_out;
    char*  ws  = (char*)d_ws;

    if (ws_size < WS_TOTAL) return;

    double* STATE = (double*)(ws + OFF_STATE);
    double* Gv    = STATE + SI_G;
    double* LOGP  = STATE + SI_LOGP;
    double* SAMP  = STATE + SI_SAMP;
    double* OUTS  = STATE + SI_OUTS;
    double* ENT   = STATE + SI_ENT;
    double* WPQ   = STATE + SI_WPQ;
    double* LGP   = STATE + SI_LGP;
    float*  H     = (float*)(ws + OFF_H);
    float*  Cc    = (float*)(ws + OFF_C);
    float*  Z     = (float*)(ws + OFF_Z);
    float*  Z1    = Z + (size_t)BKR * G4;
    float*  H2    = (float*)(ws + OFF_H2);
    float*  C2    = (float*)(ws + OFF_C2);
    float*  HD    = (float*)(ws + OFF_HD);
    float*  EMB   = (float*)(ws + OFF_EMB);
    float*  XFW   = (float*)(ws + OFF_XFW);
    float*  BIAS  = (float*)(ws + OFF_BIAS);
    double* LPT   = (double*)(ws + OFF_LPT);
    double* GMAT  = (double*)(ws + OFF_GMAT);
    int*    ORDER = (int*)(ws + OFF_INTS);
    int*    GREEDY= ORDER + 512;

    hipMemsetAsync(ws, 0, ZERO_END, stream);
    ij_bias_kernel<<<32, 256, 0, stream>>>(b_ih, b_hh, BIAS);

    // xfW = x_f @ W_ih[:, :2048]^T  (one-time, fp32 vector GEMM, M=64)
    ij_gemm_f32<<<dim3(128, 1, 4), 256, 0, stream>>>(
        x_f, nullptr, nullptr, 1 << 30, 1 << 30, 2048, 0, 0,
        W_ih, nullptr, 1 << 30, 4224, 0,
        Z, BB, G4, 512);
    ij_reduce_xfw_kernel<<<2048, 256, 0, stream>>>(Z, XFW);

    for (int t = 0; t < TT; ++t) {
        const int* pop_t = pop + t * BKR;
        ij_emb_kernel<<<256, 256, 0, stream>>>(W_emb, b_emb, pop_t, EMB);

        // gate GEMM (MFMA f16-split): A=[emb|xf3_t|h], B=[W_ih cols 2048..|W_hh]
        // split-K=2 partials; lstm fuses reduce + xfW + bias.
        ij_gemm_f16x3<<<dim3(64, 4, 2), 256, 0, stream>>>(
            EMB, x_f3 + (size_t)t * BKR * 2048, H, 128, 2176, 128, 2048, 2048,
            W_ih + 2048, W_hh, 2176, 4224, 2048,
            Z, G4, 2112);

        ij_lstm_kernel<<<4096, 256, 0, stream>>>(Z, Z1, XFW, BIAS, Cc, H2, C2);

        // fc1 (MFMA, split-K=4; reduce w/ bias+relu)
        ij_gemm_f16x3<<<dim3(16, 4, 4), 256, 0, stream>>>(
            H2, nullptr, nullptr, 1 << 30, 1 << 30, 2048, 0, 0,
            W_fc1, nullptr, 1 << 30, 2048, 0,
            Z, HH, 512);
        ij_reduce_fc1_kernel<<<4096, 256, 0, stream>>>(Z, b_fc1, HD);

        // logits (MFMA, split-K=16; reduce folded into softmax kernel)
        ij_gemm_f16x3<<<dim3(4, 4, 16), 256, 0, stream>>>(
            HD, nullptr, nullptr, 1 << 30, 1 << 30, 2048, 0, 0,
            W_out, nullptr, 1 << 30, 2048, 0,
            Z, DD, 128);

        ij_softmax_g_kernel<<<512, 256, 0, stream>>>(
            Z, b_out, mask, pop_t, gum + (size_t)t * BKR * DD,
            Gv, LOGP, LPT, GMAT, GREEDY);

        ij_beam_kernel<<<64, 256, 0, stream>>>(
            GMAT, LPT, GREEDY, pop_t, mask,
            Gv, LOGP, SAMP, OUTS, ENT, WPQ, LGP, ORDER, t);

        ij_permute_kernel<<<4096, 256, 0, stream>>>(H2, C2, ORDER, H, Cc);
    }

    ij_final_kernel<<<25, 256, 0, stream>>>(OUTS, SAMP, ENT, WPQ, LGP, out);
    (void)in_sizes; (void)n_in; (void)out_size;
}